// Round 2
// baseline (1610.392 us; speedup 1.0000x reference)
//
#include <hip/hip_runtime.h>

#define BN 16
#define LN 512
#define HN 1024
#define KN 8192
#define TK 64
#define NTHREADS 512

typedef float  f32x4  __attribute__((ext_vector_type(4)));
typedef __bf16 bf16x8 __attribute__((ext_vector_type(8)));
typedef __bf16 bf16x4 __attribute__((ext_vector_type(4)));

#define XT_LDA 72   // 64 + 8 pad (bf16) -> 144B row stride
#define WT_LDA 72
#define AT_LDA 520  // 512 + 8 pad
#define X2_LDA 72

struct __align__(16) SMem {
  __bf16 attn[TK][AT_LDA];          // 66,560 B
  union {
    struct {
      __bf16 xt[LN][XT_LDA];        // 73,728 B
      __bf16 wt[TK][WT_LDA];        //  9,216 B
    } p1;
    __bf16 x2[512][X2_LDA];         // 73,728 B (transposed X tile: [h-local][l-local])
  } u;
  float redM[8][TK];
  float redS[8][TK];
  float Mf[TK];
  float Sinv[TK];
};                                   // total 154,112 B < 160 KiB

__device__ __forceinline__ bf16x4 cvt4(float4 v) {
  bf16x4 r;
  r[0] = (__bf16)v.x; r[1] = (__bf16)v.y; r[2] = (__bf16)v.z; r[3] = (__bf16)v.w;
  return r;
}

__global__ __launch_bounds__(NTHREADS, 2)
void mlattn_fused(const float* __restrict__ X, const int* __restrict__ Mk,
                  const float* __restrict__ W, float* __restrict__ out) {
  __shared__ SMem sm;
  const int t    = threadIdx.x;
  const int wv   = t >> 6;
  const int lane = t & 63;
  const int q    = lane >> 4;   // quad
  const int c    = lane & 15;
  const int b    = blockIdx.y;
  const int k0   = blockIdx.x * TK;
  const float* Xb = X + (size_t)b * LN * HN;
  const f32x4 fzero = {0.f, 0.f, 0.f, 0.f};

  // ================= Phase 1: S[64][512] = W_tile @ Xb^T (contract over h) ====
  // wave wv owns l-columns [wv*64, wv*64+64), all 64 k-rows.
  f32x4 acc[4][4];
  #pragma unroll
  for (int mt = 0; mt < 4; ++mt)
    #pragma unroll
    for (int nt = 0; nt < 4; ++nt)
      acc[mt][nt] = fzero;

  const int lw0 = wv * 64;
  const int sr  = t >> 4;   // 0..31
  const int sc  = t & 15;   // 0..15

  for (int h0 = 0; h0 < HN; h0 += 64) {
    #pragma unroll
    for (int p = 0; p < 2; ++p) {            // W tile: 64 x 64
      const int row = p * 32 + sr;
      float4 v = *(const float4*)(W + (size_t)(k0 + row) * HN + h0 + sc * 4);
      *(bf16x4*)&sm.u.p1.wt[row][sc * 4] = cvt4(v);
    }
    #pragma unroll
    for (int p = 0; p < 16; ++p) {           // X tile: 512 x 64
      const int row = p * 32 + sr;
      float4 v = *(const float4*)(Xb + (size_t)row * HN + h0 + sc * 4);
      *(bf16x4*)&sm.u.p1.xt[row][sc * 4] = cvt4(v);
    }
    __syncthreads();
    #pragma unroll
    for (int ks = 0; ks < 2; ++ks) {
      bf16x8 aF[4], bF[4];
      #pragma unroll
      for (int mt = 0; mt < 4; ++mt)
        aF[mt] = *(const bf16x8*)&sm.u.p1.wt[mt * 16 + c][ks * 32 + q * 8];
      #pragma unroll
      for (int nt = 0; nt < 4; ++nt)
        bF[nt] = *(const bf16x8*)&sm.u.p1.xt[lw0 + nt * 16 + c][ks * 32 + q * 8];
      #pragma unroll
      for (int mt = 0; mt < 4; ++mt)
        #pragma unroll
        for (int nt = 0; nt < 4; ++nt)
          acc[mt][nt] = __builtin_amdgcn_mfma_f32_16x16x32_bf16(aF[mt], bF[nt], acc[mt][nt], 0, 0, 0);
    }
    __syncthreads();
  }

  // apply mask (reference: masked -> -inf before softmax). Mask is bool->int32.
  // D-layout: col=lane&15, row=(lane>>4)*4+reg.
  #pragma unroll
  for (int nt = 0; nt < 4; ++nt) {
    const int m = Mk[b * LN + lw0 + nt * 16 + c];
    if (!m) {
      #pragma unroll
      for (int mt = 0; mt < 4; ++mt)
        #pragma unroll
        for (int r = 0; r < 4; ++r)
          acc[mt][nt][r] = -1e30f;
    }
  }

  // ---- softmax over l: per-wave partials over its 64 cols, LDS cross-wave reduce ----
  float pm[4][4];
  #pragma unroll
  for (int mt = 0; mt < 4; ++mt)
    #pragma unroll
    for (int r = 0; r < 4; ++r)
      pm[mt][r] = fmaxf(fmaxf(acc[mt][0][r], acc[mt][1][r]), fmaxf(acc[mt][2][r], acc[mt][3][r]));
  #pragma unroll
  for (int off = 1; off < 16; off <<= 1)
    #pragma unroll
    for (int mt = 0; mt < 4; ++mt)
      #pragma unroll
      for (int r = 0; r < 4; ++r)
        pm[mt][r] = fmaxf(pm[mt][r], __shfl_xor(pm[mt][r], off, 64));
  if (c == 0) {
    #pragma unroll
    for (int mt = 0; mt < 4; ++mt)
      #pragma unroll
      for (int r = 0; r < 4; ++r)
        sm.redM[wv][mt * 16 + q * 4 + r] = pm[mt][r];
  }
  __syncthreads();
  if (t < TK) {
    float m = sm.redM[0][t];
    #pragma unroll
    for (int w = 1; w < 8; ++w) m = fmaxf(m, sm.redM[w][t]);
    sm.Mf[t] = m;
  }
  __syncthreads();

  float ps[4][4];
  #pragma unroll
  for (int mt = 0; mt < 4; ++mt)
    #pragma unroll
    for (int r = 0; r < 4; ++r) {
      const float M = sm.Mf[mt * 16 + q * 4 + r];
      float s = 0.f;
      #pragma unroll
      for (int nt = 0; nt < 4; ++nt) {
        const float e = __expf(acc[mt][nt][r] - M);
        acc[mt][nt][r] = e;
        s += e;
      }
      ps[mt][r] = s;
    }
  #pragma unroll
  for (int off = 1; off < 16; off <<= 1)
    #pragma unroll
    for (int mt = 0; mt < 4; ++mt)
      #pragma unroll
      for (int r = 0; r < 4; ++r)
        ps[mt][r] += __shfl_xor(ps[mt][r], off, 64);
  if (c == 0) {
    #pragma unroll
    for (int mt = 0; mt < 4; ++mt)
      #pragma unroll
      for (int r = 0; r < 4; ++r)
        sm.redS[wv][mt * 16 + q * 4 + r] = ps[mt][r];
  }
  __syncthreads();
  if (t < TK) {
    float s = 0.f;
    #pragma unroll
    for (int w = 0; w < 8; ++w) s += sm.redS[w][t];
    sm.Sinv[t] = 1.f / s;
  }
  __syncthreads();

  // normalized attn -> LDS (A-operand layout for phase 2: row-major [k-row][l])
  #pragma unroll
  for (int mt = 0; mt < 4; ++mt)
    #pragma unroll
    for (int r = 0; r < 4; ++r) {
      const int row = mt * 16 + q * 4 + r;
      const float inv = sm.Sinv[row];
      #pragma unroll
      for (int nt = 0; nt < 4; ++nt)
        sm.attn[row][lw0 + nt * 16 + c] = (__bf16)(acc[mt][nt][r] * inv);
    }

  // ================= Phase 2: O[64][1024] = attn @ Xb (contract over l) =======
  // wave: M-half = wv>>2 (32 rows), N-quarter = wv&3 (128 of the staged 512 h cols)
  const int wM = wv >> 2;
  const int wN = wv & 3;
  f32x4 acc2[2][16];
  #pragma unroll
  for (int i = 0; i < 2; ++i)
    #pragma unroll
    for (int j = 0; j < 16; ++j)
      acc2[i][j] = fzero;

  for (int lc = 0; lc < 8; ++lc) {
    const int l0c = lc * 64;
    #pragma unroll
    for (int hh = 0; hh < 2; ++hh) {
      __syncthreads();
      // stage transposed tile: x2[h-local = t][l-local], lane-per-row (coalesced dword loads)
      {
        const float* xcol = Xb + (size_t)hh * 512 + t;
        #pragma unroll
        for (int u = 0; u < 16; ++u) {
          const int l = l0c + u * 4;
          const float d0 = xcol[(size_t)(l + 0) * HN];
          const float d1 = xcol[(size_t)(l + 1) * HN];
          const float d2 = xcol[(size_t)(l + 2) * HN];
          const float d3 = xcol[(size_t)(l + 3) * HN];
          bf16x4 p;
          p[0] = (__bf16)d0; p[1] = (__bf16)d1; p[2] = (__bf16)d2; p[3] = (__bf16)d3;
          *(bf16x4*)&sm.u.x2[t][u * 4] = p;
        }
      }
      __syncthreads();
      #pragma unroll
      for (int ks = 0; ks < 2; ++ks) {
        bf16x8 aF2[2], bF2[8];
        #pragma unroll
        for (int mt = 0; mt < 2; ++mt)
          aF2[mt] = *(const bf16x8*)&sm.attn[wM * 32 + mt * 16 + c][l0c + ks * 32 + q * 8];
        #pragma unroll
        for (int nt = 0; nt < 8; ++nt)
          bF2[nt] = *(const bf16x8*)&sm.u.x2[wN * 128 + nt * 16 + c][ks * 32 + q * 8];
        #pragma unroll
        for (int mt = 0; mt < 2; ++mt)
          #pragma unroll
          for (int nt = 0; nt < 8; ++nt)
            acc2[mt][hh * 8 + nt] =
                __builtin_amdgcn_mfma_f32_16x16x32_bf16(aF2[mt], bF2[nt], acc2[mt][hh * 8 + nt], 0, 0, 0);
      }
    }
  }

  // epilogue: D col = lane&15 (h), row = q*4+reg (k)
  float* outb = out + ((size_t)b * KN + k0) * HN;
  #pragma unroll
  for (int mt = 0; mt < 2; ++mt) {
    #pragma unroll
    for (int j = 0; j < 16; ++j) {
      const int hh = j >> 3, nt = j & 7;
      const int h = hh * 512 + wN * 128 + nt * 16 + c;
      #pragma unroll
      for (int r = 0; r < 4; ++r) {
        const int krow = wM * 32 + mt * 16 + q * 4 + r;
        outb[(size_t)krow * HN + h] = acc2[mt][j][r];
      }
    }
  }
}

extern "C" void kernel_launch(void* const* d_in, const int* in_sizes, int n_in,
                              void* d_out, int out_size, void* d_ws, size_t ws_size,
                              hipStream_t stream) {
  (void)in_sizes; (void)n_in; (void)d_ws; (void)ws_size; (void)out_size;
  const float* X = (const float*)d_in[0];
  const int* Mk = (const int*)d_in[1];
  const float* W = (const float*)d_in[2];
  float* out = (float*)d_out;
  dim3 grid(KN / TK, BN);
  mlattn_fused<<<grid, NTHREADS, 0, stream>>>(X, Mk, W, out);
}